// Round 1
// baseline (894.317 us; speedup 1.0000x reference)
//
#include <hip/hip_runtime.h>
#include <math.h>

// Problem constants
#define NB 8
#define LQ 64
#define LP 512
#define NV 32
#define DIM 512
#define NH 8
#define HD 64

// ---------------------------------------------------------------------------
// K1a: partial sums of memory over Lp chunks. grid = 2048 (= 8*32 bv * 8 ch),
// block = 256. part[bv][ch][c] = sum_{l in chunk} memory[b][l][v][c]
// ---------------------------------------------------------------------------
__global__ __launch_bounds__(256) void k_part(const float* __restrict__ mem,
                                              float* __restrict__ part) {
  int blk = blockIdx.x;
  int bv = blk >> 3, ch = blk & 7;
  int b = bv >> 5, v = bv & 31;
  int tid = threadIdx.x;
  float a0 = 0.f, a1 = 0.f;
  int l0 = ch * 64;
  for (int l = l0; l < l0 + 64; ++l) {
    const float* row = mem + (((size_t)b * LP + l) * NV + v) * DIM;
    a0 += row[tid];
    a1 += row[tid + 256];
  }
  float* dst = part + ((size_t)bv * 8 + ch) * DIM;
  dst[tid] = a0;
  dst[tid + 256] = a1;
}

// K1b: reduce chunks -> mmean[b][v][c] (mean over Lp=512). grid=512, block=256
__global__ __launch_bounds__(256) void k_mean(const float* __restrict__ part,
                                              float* __restrict__ mmean) {
  int o = blockIdx.x * 256 + threadIdx.x;  // 131072 outputs
  int bv = o >> 9, c = o & 511;
  float s = 0.f;
#pragma unroll
  for (int ch = 0; ch < 8; ++ch) s += part[((size_t)bv * 8 + ch) * 512 + c];
  mmean[o] = s * (1.0f / 512.0f);
}

// ---------------------------------------------------------------------------
// Generic f32 GEMM: C[M x 512] = A[M x 512] @ B[512 x 512] (+ bias)
// grid = (M/64, 8), block = 256. 64x64 tile, K-step 16, 4x4 per thread.
// ---------------------------------------------------------------------------
#define FMA16()                                         \
  do {                                                  \
    acc[0][0] = fmaf(a4.x, b4.x, acc[0][0]);            \
    acc[0][1] = fmaf(a4.x, b4.y, acc[0][1]);            \
    acc[0][2] = fmaf(a4.x, b4.z, acc[0][2]);            \
    acc[0][3] = fmaf(a4.x, b4.w, acc[0][3]);            \
    acc[1][0] = fmaf(a4.y, b4.x, acc[1][0]);            \
    acc[1][1] = fmaf(a4.y, b4.y, acc[1][1]);            \
    acc[1][2] = fmaf(a4.y, b4.z, acc[1][2]);            \
    acc[1][3] = fmaf(a4.y, b4.w, acc[1][3]);            \
    acc[2][0] = fmaf(a4.z, b4.x, acc[2][0]);            \
    acc[2][1] = fmaf(a4.z, b4.y, acc[2][1]);            \
    acc[2][2] = fmaf(a4.z, b4.z, acc[2][2]);            \
    acc[2][3] = fmaf(a4.z, b4.w, acc[2][3]);            \
    acc[3][0] = fmaf(a4.w, b4.x, acc[3][0]);            \
    acc[3][1] = fmaf(a4.w, b4.y, acc[3][1]);            \
    acc[3][2] = fmaf(a4.w, b4.z, acc[3][2]);            \
    acc[3][3] = fmaf(a4.w, b4.w, acc[3][3]);            \
  } while (0)

__global__ __launch_bounds__(256) void gemm512(const float* __restrict__ A,
                                               const float* __restrict__ Bm,
                                               const float* __restrict__ bias,
                                               float* __restrict__ C) {
  __shared__ float As[16][68];  // [k][m], padded to kill write conflicts
  __shared__ float Bs[16][64];  // [k][n]
  int tid = threadIdx.x;
  int tm = tid & 15, tn = tid >> 4;
  int row0 = blockIdx.x * 64, col0 = blockIdx.y * 64;
  float acc[4][4] = {};
  int ja = tid >> 2, ka4 = (tid & 3) * 4;
  int kb = tid >> 4, nb4 = (tid & 15) * 4;
  for (int k0 = 0; k0 < 512; k0 += 16) {
    float4 av = *(const float4*)(A + (size_t)(row0 + ja) * 512 + k0 + ka4);
    As[ka4 + 0][ja] = av.x;
    As[ka4 + 1][ja] = av.y;
    As[ka4 + 2][ja] = av.z;
    As[ka4 + 3][ja] = av.w;
    *(float4*)&Bs[kb][nb4] =
        *(const float4*)(Bm + (size_t)(k0 + kb) * 512 + col0 + nb4);
    __syncthreads();
#pragma unroll
    for (int k = 0; k < 16; ++k) {
      float4 a4 = *(const float4*)&As[k][tm * 4];
      float4 b4 = *(const float4*)&Bs[k][tn * 4];
      FMA16();
    }
    __syncthreads();
  }
#pragma unroll
  for (int ii = 0; ii < 4; ++ii) {
    int row = row0 + tm * 4 + ii;
    float4 o;
    o.x = acc[ii][0];
    o.y = acc[ii][1];
    o.z = acc[ii][2];
    o.w = acc[ii][3];
    if (bias) {
      o.x += bias[col0 + tn * 4 + 0];
      o.y += bias[col0 + tn * 4 + 1];
      o.z += bias[col0 + tn * 4 + 2];
      o.w += bias[col0 + tn * 4 + 3];
    }
    *(float4*)(C + (size_t)row * 512 + col0 + tn * 4) = o;
  }
}

// ---------------------------------------------------------------------------
// K2c: channel scores + softmax + w_sum. One block per (b,h), 64 blocks.
// qc[q][hd] = qlin rows [8h,8h+8) flat (faithful raw reshape);
// kc[v'][hd] = kclin rows [4h,4h+4) flat.
// ---------------------------------------------------------------------------
__global__ __launch_bounds__(256) void k_ch(const float* __restrict__ qlin,
                                            const float* __restrict__ kclin,
                                            float* __restrict__ wsum) {
  __shared__ float qcs[4096];  // [q][hd]
  __shared__ float kcs[2048];  // [v][hd]
  __shared__ float sc[2048];   // [q][v]
  int bh = blockIdx.x;
  int b = bh >> 3, h = bh & 7;
  int tid = threadIdx.x;
  const float* qsrc = qlin + ((size_t)b * LQ + h * 8) * DIM;
  for (int s = tid; s < 4096; s += 256) qcs[s] = qsrc[s];
  const float* ksrc = kclin + ((size_t)b * NV + h * 4) * DIM;
  for (int s = tid; s < 2048; s += 256) kcs[s] = ksrc[s];
  __syncthreads();
  for (int s = tid; s < 2048; s += 256) {
    int q = s >> 5, v = s & 31;
    float acc = 0.f;
#pragma unroll 8
    for (int d = 0; d < 64; ++d) acc = fmaf(qcs[q * 64 + d], kcs[v * 64 + d], acc);
    sc[s] = acc * 8.0f;  // "/ SCALE" with SCALE = hd^-0.5 = 0.125
  }
  __syncthreads();
  if (tid < 64) {
    int q = tid;
    float m = -INFINITY;
    for (int v = 0; v < 32; ++v) m = fmaxf(m, sc[q * 32 + v]);
    float sum = 0.f;
    for (int v = 0; v < 32; ++v) {
      float e = __expf(sc[q * 32 + v] - m);
      sc[q * 32 + v] = e;
      sum += e;
    }
    float inv = 1.0f / sum;
    for (int v = 0; v < 32; ++v) sc[q * 32 + v] *= inv;
  }
  __syncthreads();
  if (tid < 32) {
    float s = 0.f;
    for (int q = 0; q < 64; ++q) s += sc[q * 32 + tid];
    wsum[(size_t)bh * 32 + tid] = s;
  }
}

// ---------------------------------------------------------------------------
// K2d: W_eff[b,h,a,c,hd] = sum_r wsum[b,h,8a+r] * Wv_c[c, r*64+hd]
// 8.4M outputs; grid = 32768, block = 256.
// ---------------------------------------------------------------------------
__global__ __launch_bounds__(256) void k_weff(const float* __restrict__ wsum,
                                              const float* __restrict__ Wv_c,
                                              float* __restrict__ weff) {
  int o = blockIdx.x * 256 + threadIdx.x;
  int hd = o & 63;
  int c = (o >> 6) & 511;
  int a = (o >> 15) & 3;
  int bh = o >> 17;
  const float* wsv = wsum + (size_t)bh * 32 + a * 8;
  const float* wr = Wv_c + (size_t)c * 512 + hd;
  float acc = 0.f;
#pragma unroll
  for (int r = 0; r < 8; ++r) acc = fmaf(wsv[r], wr[r * 64], acc);
  weff[o] = acc;
}

// ---------------------------------------------------------------------------
// K3: stage-1 aggregation GEMM. One block per (b,h,i) = 512 blocks.
// out[j][hd] = sum_{a,c} memory[b][64h+j][4i+a][c] * W_eff[b,h,a,c,hd]
// written to mem_agg[b][8j+i][64h+hd]. M=64, N=64, K=2048.
// ---------------------------------------------------------------------------
__global__ __launch_bounds__(256) void k_stage1(const float* __restrict__ mem,
                                                const float* __restrict__ weff,
                                                float* __restrict__ magg) {
  __shared__ float As[16][68];
  __shared__ float Bs[16][64];
  int blk = blockIdx.x;  // b*64 + h*8 + i
  int b = blk >> 6, h = (blk >> 3) & 7, i = blk & 7;
  int bh = b * 8 + h;
  int tid = threadIdx.x;
  int tm = tid & 15, tn = tid >> 4;
  float acc[4][4] = {};
  int ja = tid >> 2, ka4 = (tid & 3) * 4;
  int kb = tid >> 4, nb4 = (tid & 15) * 4;
  for (int kt = 0; kt < 128; ++kt) {
    int k0 = kt * 16;
    int a = k0 >> 9, c0 = k0 & 511;
    const float* arow = mem +
        (((size_t)b * LP + (h * 64 + ja)) * NV + (4 * i + a)) * DIM + c0 + ka4;
    float4 av = *(const float4*)arow;
    As[ka4 + 0][ja] = av.x;
    As[ka4 + 1][ja] = av.y;
    As[ka4 + 2][ja] = av.z;
    As[ka4 + 3][ja] = av.w;
    *(float4*)&Bs[kb][nb4] = *(const float4*)(
        weff + ((size_t)(bh * 4 + a) * 512 + c0 + kb) * 64 + nb4);
    __syncthreads();
#pragma unroll
    for (int k = 0; k < 16; ++k) {
      float4 a4 = *(const float4*)&As[k][tm * 4];
      float4 b4 = *(const float4*)&Bs[k][tn * 4];
      FMA16();
    }
    __syncthreads();
  }
#pragma unroll
  for (int ii = 0; ii < 4; ++ii) {
    int j = tm * 4 + ii;
    float4 o;
    o.x = acc[ii][0];
    o.y = acc[ii][1];
    o.z = acc[ii][2];
    o.w = acc[ii][3];
    *(float4*)(magg + ((size_t)b * LP + 8 * j + i) * DIM + h * 64 + tn * 4) = o;
  }
}

// ---------------------------------------------------------------------------
// K4c: stage-2 attention, flash-style online softmax. One block per (b,h).
// block = 256: thread = (qrow 0..63, quad 0..3); quad owns 16 of 64 hd.
// ---------------------------------------------------------------------------
__global__ __launch_bounds__(256) void k_attn(const float* __restrict__ q2,
                                              const float* __restrict__ kmat,
                                              const float* __restrict__ vmat,
                                              float* __restrict__ attn) {
  __shared__ float Qs[4096];
  __shared__ float Ks[4096];
  __shared__ float Vs[4096];
  int bh = blockIdx.x;
  int b = bh >> 3, h = bh & 7;
  int tid = threadIdx.x;
  for (int s = tid; s < 4096; s += 256) {
    int q = s >> 6, hd = s & 63;
    Qs[s] = q2[((size_t)b * LQ + q) * DIM + h * 64 + hd];
  }
  __syncthreads();
  int qr = tid >> 2, quad = tid & 3;
  float qreg[16];
#pragma unroll
  for (int j = 0; j < 16; ++j) qreg[j] = Qs[qr * 64 + quad * 16 + j];
  float m = -INFINITY, l = 0.f;
  float acc[16] = {};
  for (int kt = 0; kt < 8; ++kt) {
    __syncthreads();
    for (int s = tid; s < 4096; s += 256) {
      int kk = s >> 6, hd = s & 63;
      size_t src = ((size_t)b * LP + kt * 64 + kk) * DIM + h * 64 + hd;
      Ks[s] = kmat[src];
      Vs[s] = vmat[src];
    }
    __syncthreads();
    for (int kk = 0; kk < 64; ++kk) {
      float p = 0.f;
      const float* kr = &Ks[kk * 64 + quad * 16];
#pragma unroll
      for (int j = 0; j < 16; ++j) p = fmaf(qreg[j], kr[j], p);
      p += __shfl_xor(p, 1);
      p += __shfl_xor(p, 2);
      float sco = p * 8.0f;  // "/ SCALE"
      float nm = fmaxf(m, sco);
      float co = __expf(m - nm);
      float po = __expf(sco - nm);
      l = l * co + po;
      const float* vr = &Vs[kk * 64 + quad * 16];
#pragma unroll
      for (int j = 0; j < 16; ++j) acc[j] = fmaf(po, vr[j], acc[j] * co);
      m = nm;
    }
  }
  float inv = 1.0f / l;
#pragma unroll
  for (int j = 0; j < 16; ++j)
    attn[((size_t)b * LQ + qr) * DIM + h * 64 + quad * 16 + j] = acc[j] * inv;
}

// ---------------------------------------------------------------------------
extern "C" void kernel_launch(void* const* d_in, const int* in_sizes, int n_in,
                              void* d_out, int out_size, void* d_ws,
                              size_t ws_size, hipStream_t stream) {
  const float* query = (const float*)d_in[0];
  const float* memory = (const float*)d_in[1];
  const float* Wq_c = (const float*)d_in[2];
  const float* Wk_c = (const float*)d_in[3];
  const float* Wv_c = (const float*)d_in[4];
  const float* Wq = (const float*)d_in[5];
  const float* Wk = (const float*)d_in[6];
  const float* Wv = (const float*)d_in[7];
  const float* Wp = (const float*)d_in[8];
  const float* bp = (const float*)d_in[9];
  float* out = (float*)d_out;
  float* ws = (float*)d_ws;

  // workspace layout (floats)
  float* part  = ws;                    // 8*32*8*512      = 1,048,576
  float* mmean = part + 1048576;        // 8*32*512        =   131,072
  float* qlin  = mmean + 131072;        // 8*64*512        =   262,144
  float* kclin = qlin + 262144;         // 8*32*512        =   131,072
  float* wsum  = kclin + 131072;        // 8*8*32          =     2,048
  float* weff  = wsum + 2048;           // 8*8*4*512*64    = 8,388,608
  float* magg  = weff + 8388608;        // 8*512*512       = 2,097,152
  float* q2    = magg + 2097152;        // 8*64*512        =   262,144
  float* kmat  = q2 + 262144;           // 8*512*512       = 2,097,152
  float* vmat  = kmat + 2097152;        // 8*512*512       = 2,097,152
  float* attn  = vmat + 2097152;        // 8*64*512        =   262,144
  // total ~16.8M floats = 67 MB

  // stage 1: mean over Lp (linearity: mean before Wk_c projection)
  k_part<<<2048, 256, 0, stream>>>(memory, part);
  k_mean<<<512, 256, 0, stream>>>(part, mmean);

  // small projections for channel attention
  gemm512<<<dim3(8, 8), 256, 0, stream>>>(query, Wq_c, nullptr, qlin);
  gemm512<<<dim3(4, 8), 256, 0, stream>>>(mmean, Wk_c, nullptr, kclin);

  // channel softmax -> w_sum, then effective weights
  k_ch<<<64, 256, 0, stream>>>(qlin, kclin, wsum);
  k_weff<<<32768, 256, 0, stream>>>(wsum, Wv_c, weff);

  // stage-1 aggregation GEMM -> mem_agg
  k_stage1<<<512, 256, 0, stream>>>(memory, weff, magg);

  // stage 2: projections
  gemm512<<<dim3(8, 8), 256, 0, stream>>>(query, Wq, nullptr, q2);
  gemm512<<<dim3(64, 8), 256, 0, stream>>>(magg, Wk, nullptr, kmat);
  gemm512<<<dim3(64, 8), 256, 0, stream>>>(magg, Wv, nullptr, vmat);

  // attention + output projection (+bias)
  k_attn<<<64, 256, 0, stream>>>(q2, kmat, vmat, attn);
  gemm512<<<dim3(8, 8), 256, 0, stream>>>(attn, Wp, bp, out);
}

// Round 2
// 705.546 us; speedup vs baseline: 1.2676x; 1.2676x over previous
//
#include <hip/hip_runtime.h>
#include <math.h>

#define NB 8
#define LQ 64
#define LP 512
#define NV 32
#define DIM 512
#define NH 8
#define HD 64

typedef __attribute__((ext_vector_type(4))) float f32x4;
typedef __attribute__((ext_vector_type(8))) short s16x8;

__device__ __forceinline__ unsigned short f2bf(float x) {
  unsigned int u = __float_as_uint(x);
  u += 0x7fff + ((u >> 16) & 1);   // round-to-nearest-even
  return (unsigned short)(u >> 16);
}
__device__ __forceinline__ float bf2f(unsigned short h) {
  return __uint_as_float(((unsigned int)h) << 16);
}

// ---------------------------------------------------------------------------
// K1a: partial sums of memory over Lp chunks (unchanged).
// ---------------------------------------------------------------------------
__global__ __launch_bounds__(256) void k_part(const float* __restrict__ mem,
                                              float* __restrict__ part) {
  int blk = blockIdx.x;
  int bv = blk >> 3, ch = blk & 7;
  int b = bv >> 5, v = bv & 31;
  int tid = threadIdx.x;
  float a0 = 0.f, a1 = 0.f;
  int l0 = ch * 64;
  for (int l = l0; l < l0 + 64; ++l) {
    const float* row = mem + (((size_t)b * LP + l) * NV + v) * DIM;
    a0 += row[tid];
    a1 += row[tid + 256];
  }
  float* dst = part + ((size_t)bv * 8 + ch) * DIM;
  dst[tid] = a0;
  dst[tid + 256] = a1;
}

// K1b: reduce chunks -> mean, write split bf16 hi/lo. grid=512, block=256
__global__ __launch_bounds__(256) void k_mean_split(
    const float* __restrict__ part, unsigned short* __restrict__ mh,
    unsigned short* __restrict__ ml) {
  int o = blockIdx.x * 256 + threadIdx.x;  // 131072 outputs
  int bv = o >> 9, c = o & 511;
  float s = 0.f;
#pragma unroll
  for (int ch = 0; ch < 8; ++ch) s += part[((size_t)bv * 8 + ch) * 512 + c];
  s *= (1.0f / 512.0f);
  unsigned short hh = f2bf(s);
  mh[o] = hh;
  ml[o] = f2bf(s - bf2f(hh));
}

// ---------------------------------------------------------------------------
// split a plain f32 array into bf16 hi/lo (A-operands). 8 elems/thread.
// ---------------------------------------------------------------------------
__global__ __launch_bounds__(256) void k_splitA(const float* __restrict__ src,
                                                unsigned short* __restrict__ dh,
                                                unsigned short* __restrict__ dl) {
  size_t t = (size_t)blockIdx.x * 256 + threadIdx.x;
  const float* p = src + t * 8;
  s16x8 vh, vl;
#pragma unroll
  for (int q = 0; q < 8; q += 4) {
    float4 x = *(const float4*)(p + q);
    unsigned short h0 = f2bf(x.x), h1 = f2bf(x.y), h2 = f2bf(x.z), h3 = f2bf(x.w);
    vh[q] = (short)h0; vh[q + 1] = (short)h1; vh[q + 2] = (short)h2; vh[q + 3] = (short)h3;
    vl[q] = (short)f2bf(x.x - bf2f(h0));
    vl[q + 1] = (short)f2bf(x.y - bf2f(h1));
    vl[q + 2] = (short)f2bf(x.z - bf2f(h2));
    vl[q + 3] = (short)f2bf(x.w - bf2f(h3));
  }
  *(s16x8*)(dh + t * 8) = vh;
  *(s16x8*)(dl + t * 8) = vl;
}

// ---------------------------------------------------------------------------
// split + TRANSPOSE 512x512 weights -> WT[n][k] bf16 hi/lo. grid (8,8,6).
// ---------------------------------------------------------------------------
__global__ __launch_bounds__(256) void k_splitWT(
    const float* W0, const float* W1, const float* W2, const float* W3,
    const float* W4, const float* W5, unsigned short* __restrict__ dh,
    unsigned short* __restrict__ dl) {
  __shared__ float tf[64][65];
  int z = blockIdx.z;
  const float* W = z == 0 ? W0 : z == 1 ? W1 : z == 2 ? W2 : z == 3 ? W3
                 : z == 4 ? W4 : W5;
  unsigned short* oh = dh + (size_t)z * 262144;
  unsigned short* ol = dl + (size_t)z * 262144;
  int r0 = blockIdx.x * 64, c0 = blockIdx.y * 64;
  int tid = threadIdx.x;
  int r = tid >> 2, cs = (tid & 3) * 16;
#pragma unroll
  for (int q = 0; q < 16; q += 4) {
    float4 w4 = *(const float4*)(W + (size_t)(r0 + r) * 512 + c0 + cs + q);
    tf[r][cs + q] = w4.x; tf[r][cs + q + 1] = w4.y;
    tf[r][cs + q + 2] = w4.z; tf[r][cs + q + 3] = w4.w;
  }
  __syncthreads();
  int c = tid >> 2, rs = (tid & 3) * 16;
  s16x8 vh0, vh1, vl0, vl1;
#pragma unroll
  for (int j = 0; j < 16; ++j) {
    float x = tf[rs + j][c];
    unsigned short hh = f2bf(x);
    unsigned short ll = f2bf(x - bf2f(hh));
    if (j < 8) { vh0[j] = (short)hh; vl0[j] = (short)ll; }
    else       { vh1[j - 8] = (short)hh; vl1[j - 8] = (short)ll; }
  }
  size_t off = (size_t)(c0 + c) * 512 + r0 + rs;
  *(s16x8*)(oh + off) = vh0; *(s16x8*)(oh + off + 8) = vh1;
  *(s16x8*)(ol + off) = vl0; *(s16x8*)(ol + off + 8) = vl1;
}

// ---------------------------------------------------------------------------
// Split-bf16 MFMA GEMM: C[M x ldc] = A[M x K] @ B^T   (B given as [N][K]).
// 64x64 tile, 4 waves of 32x32, BK=64, 3-term split. grid (M/64, N/64).
// ---------------------------------------------------------------------------
#define STAGE16(dst, src)                                                     \
  do {                                                                        \
    *(s16x8*)((char*)(dst) + sr * 128 + ((sb) ^ swz)) = *(const s16x8*)(src); \
    *(s16x8*)((char*)(dst) + sr * 128 + (((sb) + 16) ^ swz)) =                \
        *(const s16x8*)((src) + 8);                                           \
  } while (0)

#define MFMA_INNER()                                                          \
  do {                                                                        \
    _Pragma("unroll") for (int ks = 0; ks < 2; ++ks) {                        \
      int kb = ks * 64 + kg * 16;                                             \
      s16x8 aH[2], aL[2], bH[2], bL[2];                                       \
      _Pragma("unroll") for (int mt = 0; mt < 2; ++mt) {                      \
        int row = wm + mt * 16 + lr;                                          \
        int off = row * 128 + (kb ^ ((row & 7) << 4));                        \
        aH[mt] = *(const s16x8*)((const char*)AsH + off);                     \
        aL[mt] = *(const s16x8*)((const char*)AsL + off);                     \
      }                                                                       \
      _Pragma("unroll") for (int nt = 0; nt < 2; ++nt) {                      \
        int row = wn + nt * 16 + lr;                                          \
        int off = row * 128 + (kb ^ ((row & 7) << 4));                        \
        bH[nt] = *(const s16x8*)((const char*)BsH + off);                     \
        bL[nt] = *(const s16x8*)((const char*)BsL + off);                     \
      }                                                                       \
      _Pragma("unroll") for (int mt = 0; mt < 2; ++mt)                        \
          _Pragma("unroll") for (int nt = 0; nt < 2; ++nt) {                  \
        acc[mt][nt] = __builtin_amdgcn_mfma_f32_16x16x32_bf16(                \
            aH[mt], bH[nt], acc[mt][nt], 0, 0, 0);                            \
        acc[mt][nt] = __builtin_amdgcn_mfma_f32_16x16x32_bf16(                \
            aH[mt], bL[nt], acc[mt][nt], 0, 0, 0);                            \
        acc[mt][nt] = __builtin_amdgcn_mfma_f32_16x16x32_bf16(                \
            aL[mt], bH[nt], acc[mt][nt], 0, 0, 0);                            \
      }                                                                       \
    }                                                                         \
  } while (0)

__global__ __launch_bounds__(256) void mgemm(
    const unsigned short* __restrict__ Ahi, const unsigned short* __restrict__ Alo,
    const unsigned short* __restrict__ Bhi, const unsigned short* __restrict__ Blo,
    const float* __restrict__ bias, float* __restrict__ C, int K, int ldc) {
  __shared__ unsigned short AsH[64 * 64], AsL[64 * 64], BsH[64 * 64], BsL[64 * 64];
  int tid = threadIdx.x;
  int m0 = blockIdx.x * 64, n0 = blockIdx.y * 64;
  int lane = tid & 63, wave = tid >> 6;
  int wm = (wave >> 1) * 32, wn = (wave & 1) * 32;
  int lr = lane & 15, kg = lane >> 4;
  int sr = tid >> 2, sb = (tid & 3) * 32;
  int swz = (sr & 7) << 4;
  f32x4 acc[2][2] = {};
  const unsigned short* pAh = Ahi + (size_t)(m0 + sr) * K + (sb >> 1);
  const unsigned short* pAl = Alo + (size_t)(m0 + sr) * K + (sb >> 1);
  const unsigned short* pBh = Bhi + (size_t)(n0 + sr) * K + (sb >> 1);
  const unsigned short* pBl = Blo + (size_t)(n0 + sr) * K + (sb >> 1);
  for (int k0 = 0; k0 < K; k0 += 64) {
    STAGE16(AsH, pAh + k0);
    STAGE16(AsL, pAl + k0);
    STAGE16(BsH, pBh + k0);
    STAGE16(BsL, pBl + k0);
    __syncthreads();
    MFMA_INNER();
    __syncthreads();
  }
#pragma unroll
  for (int mt = 0; mt < 2; ++mt)
#pragma unroll
    for (int nt = 0; nt < 2; ++nt) {
      int col = n0 + wn + nt * 16 + lr;
      float badd = bias ? bias[col] : 0.f;
      int rowb = m0 + wm + mt * 16 + kg * 4;
#pragma unroll
      for (int r = 0; r < 4; ++r)
        C[(size_t)(rowb + r) * ldc + col] = acc[mt][nt][r] + badd;
    }
}

// ---------------------------------------------------------------------------
// K2c: channel scores + softmax + w_sum (unchanged). grid 64.
// ---------------------------------------------------------------------------
__global__ __launch_bounds__(256) void k_ch(const float* __restrict__ qlin,
                                            const float* __restrict__ kclin,
                                            float* __restrict__ wsum) {
  __shared__ float qcs[4096];
  __shared__ float kcs[2048];
  __shared__ float sc[2048];
  int bh = blockIdx.x;
  int b = bh >> 3, h = bh & 7;
  int tid = threadIdx.x;
  const float* qsrc = qlin + ((size_t)b * LQ + h * 8) * DIM;
  for (int s = tid; s < 4096; s += 256) qcs[s] = qsrc[s];
  const float* ksrc = kclin + ((size_t)b * NV + h * 4) * DIM;
  for (int s = tid; s < 2048; s += 256) kcs[s] = ksrc[s];
  __syncthreads();
  for (int s = tid; s < 2048; s += 256) {
    int q = s >> 5, v = s & 31;
    float acc = 0.f;
#pragma unroll 8
    for (int d = 0; d < 64; ++d) acc = fmaf(qcs[q * 64 + d], kcs[v * 64 + d], acc);
    sc[s] = acc * 8.0f;
  }
  __syncthreads();
  if (tid < 64) {
    int q = tid;
    float m = -INFINITY;
    for (int v = 0; v < 32; ++v) m = fmaxf(m, sc[q * 32 + v]);
    float sum = 0.f;
    for (int v = 0; v < 32; ++v) {
      float e = __expf(sc[q * 32 + v] - m);
      sc[q * 32 + v] = e;
      sum += e;
    }
    float inv = 1.0f / sum;
    for (int v = 0; v < 32; ++v) sc[q * 32 + v] *= inv;
  }
  __syncthreads();
  if (tid < 32) {
    float s = 0.f;
    for (int q = 0; q < 64; ++q) s += sc[q * 32 + tid];
    wsum[(size_t)bh * 32 + tid] = s;
  }
}

// ---------------------------------------------------------------------------
// K2d: W_effT[bh][hd][a*512+c] = sum_r wsum[bh][a*8+r] * Wv_c[c][r*64+hd]
// TRANSPOSED + split bf16 output. block=(bh,a): grid 256.
// ---------------------------------------------------------------------------
__global__ __launch_bounds__(256) void k_weff(const float* __restrict__ wsum,
                                              const float* __restrict__ Wv_c,
                                              unsigned short* __restrict__ wth,
                                              unsigned short* __restrict__ wtl) {
  __shared__ float tf[64][65];
  int bh = blockIdx.x >> 2, a = blockIdx.x & 3;
  int tid = threadIdx.x;
  float wsv[8];
#pragma unroll
  for (int r = 0; r < 8; ++r) wsv[r] = wsum[(size_t)bh * 32 + a * 8 + r];
  int cl = tid >> 2, hg = (tid & 3) * 16;  // compute phase: c-local, hd group
  int hd = tid >> 2, cs = (tid & 3) * 16;  // write phase: hd row, c seg
  for (int c0 = 0; c0 < 512; c0 += 64) {
    float v[16] = {};
#pragma unroll
    for (int r = 0; r < 8; ++r) {
      const float* wp = Wv_c + (size_t)(c0 + cl) * 512 + r * 64 + hg;
#pragma unroll
      for (int j = 0; j < 16; j += 4) {
        float4 w4 = *(const float4*)(wp + j);
        v[j] = fmaf(wsv[r], w4.x, v[j]);
        v[j + 1] = fmaf(wsv[r], w4.y, v[j + 1]);
        v[j + 2] = fmaf(wsv[r], w4.z, v[j + 2]);
        v[j + 3] = fmaf(wsv[r], w4.w, v[j + 3]);
      }
    }
    __syncthreads();
#pragma unroll
    for (int j = 0; j < 16; ++j) tf[cl][hg + j] = v[j];
    __syncthreads();
    s16x8 vh0, vh1, vl0, vl1;
#pragma unroll
    for (int j = 0; j < 16; ++j) {
      float x = tf[cs + j][hd];
      unsigned short hh = f2bf(x);
      unsigned short ll = f2bf(x - bf2f(hh));
      if (j < 8) { vh0[j] = (short)hh; vl0[j] = (short)ll; }
      else       { vh1[j - 8] = (short)hh; vl1[j - 8] = (short)ll; }
    }
    size_t off = ((size_t)bh * 64 + hd) * 2048 + a * 512 + c0 + cs;
    *(s16x8*)(wth + off) = vh0; *(s16x8*)(wth + off + 8) = vh1;
    *(s16x8*)(wtl + off) = vl0; *(s16x8*)(wtl + off + 8) = vl1;
  }
}

// ---------------------------------------------------------------------------
// K3: stage-1 aggregation GEMM, split-bf16 MFMA, K=2048. grid 512.
// A = memory rows (f32, converted on the fly), B = weffT (presplit).
// Output written pre-split to magg_hi/lo. XCD swizzle keeps each bh's
// weffT slice on one XCD.
// ---------------------------------------------------------------------------
__global__ __launch_bounds__(256) void k_stage1m(
    const float* __restrict__ mem, const unsigned short* __restrict__ WTh,
    const unsigned short* __restrict__ WTl, unsigned short* __restrict__ mgh,
    unsigned short* __restrict__ mgl) {
  __shared__ unsigned short AsH[64 * 64], AsL[64 * 64], BsH[64 * 64], BsL[64 * 64];
  int P = blockIdx.x;
  int blk = (P & 7) * 64 + (P >> 3);  // same bh -> same XCD
  int b = blk >> 6, h = (blk >> 3) & 7, i = blk & 7;
  int bh = b * 8 + h;
  int tid = threadIdx.x;
  int lane = tid & 63, wave = tid >> 6;
  int wm = (wave >> 1) * 32, wn = (wave & 1) * 32;
  int lr = lane & 15, kg = lane >> 4;
  int sr = tid >> 2, sb = (tid & 3) * 32;
  int swz = (sr & 7) << 4;
  f32x4 acc[2][2] = {};
  const float* abase =
      mem + ((size_t)(b * 512 + h * 64 + sr) * 32 + 4 * i) * 512 + (tid & 3) * 16;
  const unsigned short* bbh = WTh + ((size_t)bh * 64 + sr) * 2048 + (sb >> 1);
  const unsigned short* bbl = WTl + ((size_t)bh * 64 + sr) * 2048 + (sb >> 1);
  for (int k0 = 0; k0 < 2048; k0 += 64) {
    s16x8 vh0, vh1, vl0, vl1;
#pragma unroll
    for (int q = 0; q < 16; q += 4) {
      float4 x = *(const float4*)(abase + k0 + q);
      unsigned short h0 = f2bf(x.x), h1 = f2bf(x.y), h2 = f2bf(x.z), h3 = f2bf(x.w);
      unsigned short l0 = f2bf(x.x - bf2f(h0)), l1 = f2bf(x.y - bf2f(h1));
      unsigned short l2 = f2bf(x.z - bf2f(h2)), l3 = f2bf(x.w - bf2f(h3));
      if (q < 8) {
        vh0[q] = (short)h0; vh0[q + 1] = (short)h1; vh0[q + 2] = (short)h2; vh0[q + 3] = (short)h3;
        vl0[q] = (short)l0; vl0[q + 1] = (short)l1; vl0[q + 2] = (short)l2; vl0[q + 3] = (short)l3;
      } else {
        vh1[q - 8] = (short)h0; vh1[q - 7] = (short)h1; vh1[q - 6] = (short)h2; vh1[q - 5] = (short)h3;
        vl1[q - 8] = (short)l0; vl1[q - 7] = (short)l1; vl1[q - 6] = (short)l2; vl1[q - 5] = (short)l3;
      }
    }
    *(s16x8*)((char*)AsH + sr * 128 + (sb ^ swz)) = vh0;
    *(s16x8*)((char*)AsH + sr * 128 + ((sb + 16) ^ swz)) = vh1;
    *(s16x8*)((char*)AsL + sr * 128 + (sb ^ swz)) = vl0;
    *(s16x8*)((char*)AsL + sr * 128 + ((sb + 16) ^ swz)) = vl1;
    STAGE16(BsH, bbh + k0);
    STAGE16(BsL, bbl + k0);
    __syncthreads();
    MFMA_INNER();
    __syncthreads();
  }
#pragma unroll
  for (int mt = 0; mt < 2; ++mt)
#pragma unroll
    for (int nt = 0; nt < 2; ++nt) {
      int hd = wn + nt * 16 + lr;
      int jb = wm + mt * 16 + kg * 4;
#pragma unroll
      for (int r = 0; r < 4; ++r) {
        int j = jb + r;
        size_t idx = ((size_t)b * 512 + 8 * j + i) * 512 + h * 64 + hd;
        float v = acc[mt][nt][r];
        unsigned short hh = f2bf(v);
        mgh[idx] = hh;
        mgl[idx] = f2bf(v - bf2f(hh));
      }
    }
}

// ---------------------------------------------------------------------------
// K4: stage-2 attention (f32 VALU, known-correct) + split epilogue. grid 64.
// ---------------------------------------------------------------------------
__global__ __launch_bounds__(256) void k_attn(const float* __restrict__ q2,
                                              const float* __restrict__ kmat,
                                              const float* __restrict__ vmat,
                                              unsigned short* __restrict__ ath,
                                              unsigned short* __restrict__ atl) {
  __shared__ float Qs[4096];
  __shared__ float Ks[4096];
  __shared__ float Vs[4096];
  int bh = blockIdx.x;
  int b = bh >> 3, h = bh & 7;
  int tid = threadIdx.x;
  for (int s = tid; s < 4096; s += 256) {
    int q = s >> 6, hd = s & 63;
    Qs[s] = q2[((size_t)b * LQ + q) * DIM + h * 64 + hd];
  }
  __syncthreads();
  int qr = tid >> 2, quad = tid & 3;
  float qreg[16];
#pragma unroll
  for (int j = 0; j < 16; ++j) qreg[j] = Qs[qr * 64 + quad * 16 + j];
  float m = -INFINITY, l = 0.f;
  float acc[16] = {};
  for (int kt = 0; kt < 8; ++kt) {
    __syncthreads();
    for (int s = tid; s < 4096; s += 256) {
      int kk = s >> 6, hd = s & 63;
      size_t src = ((size_t)b * LP + kt * 64 + kk) * DIM + h * 64 + hd;
      Ks[s] = kmat[src];
      Vs[s] = vmat[src];
    }
    __syncthreads();
    for (int kk = 0; kk < 64; ++kk) {
      float p = 0.f;
      const float* kr = &Ks[kk * 64 + quad * 16];
#pragma unroll
      for (int j = 0; j < 16; ++j) p = fmaf(qreg[j], kr[j], p);
      p += __shfl_xor(p, 1);
      p += __shfl_xor(p, 2);
      float sco = p * 8.0f;
      float nm = fmaxf(m, sco);
      float co = __expf(m - nm);
      float po = __expf(sco - nm);
      l = l * co + po;
      const float* vr = &Vs[kk * 64 + quad * 16];
#pragma unroll
      for (int j = 0; j < 16; ++j) acc[j] = fmaf(po, vr[j], acc[j] * co);
      m = nm;
    }
  }
  float inv = 1.0f / l;
  s16x8 vh0, vh1, vl0, vl1;
#pragma unroll
  for (int j = 0; j < 16; ++j) {
    float o = acc[j] * inv;
    unsigned short hh = f2bf(o);
    unsigned short ll = f2bf(o - bf2f(hh));
    if (j < 8) { vh0[j] = (short)hh; vl0[j] = (short)ll; }
    else       { vh1[j - 8] = (short)hh; vl1[j - 8] = (short)ll; }
  }
  size_t ob = ((size_t)b * LQ + qr) * DIM + h * 64 + quad * 16;
  *(s16x8*)(ath + ob) = vh0; *(s16x8*)(ath + ob + 8) = vh1;
  *(s16x8*)(atl + ob) = vl0; *(s16x8*)(atl + ob + 8) = vl1;
}

// ---------------------------------------------------------------------------
extern "C" void kernel_launch(void* const* d_in, const int* in_sizes, int n_in,
                              void* d_out, int out_size, void* d_ws,
                              size_t ws_size, hipStream_t stream) {
  const float* query = (const float*)d_in[0];
  const float* memory = (const float*)d_in[1];
  const float* Wq_c = (const float*)d_in[2];
  const float* Wk_c = (const float*)d_in[3];
  const float* Wv_c = (const float*)d_in[4];
  const float* Wq = (const float*)d_in[5];
  const float* Wk = (const float*)d_in[6];
  const float* Wv = (const float*)d_in[7];
  const float* Wp = (const float*)d_in[8];
  const float* bp = (const float*)d_in[9];
  float* out = (float*)d_out;
  float* ws = (float*)d_ws;

  // -------- workspace layout (float units) — 13,502,464 floats = 54 MB ----
  float* part = ws;  // [0, 1048576) — dead after k_mean; region reused:
  float* qlin = ws;                       // 262144 f32
  float* kclin = ws + 262144;             // 131072 f32
  float* q2 = ws + 393216;                // 262144 f32
  unsigned short* ath = (unsigned short*)(ws + 655360);   // 262144 bf16
  unsigned short* atl = (unsigned short*)(ws + 786432);   // 262144 bf16
  unsigned short* mmh = (unsigned short*)(ws + 1048576);  // 131072 bf16
  unsigned short* mml = (unsigned short*)(ws + 1114112);
  unsigned short* qh = (unsigned short*)(ws + 1179648);   // 262144 bf16
  unsigned short* ql = (unsigned short*)(ws + 1310720);
  unsigned short* WTh = (unsigned short*)(ws + 1441792);  // 6*262144 bf16
  unsigned short* WTl = (unsigned short*)(ws + 2228224);
  float* wsum = ws + 3014656;             // 2048 f32
  unsigned short* wth = (unsigned short*)(ws + 3016704);  // 8388608 bf16
  unsigned short* wtl = (unsigned short*)(ws + 7211008);  // 8388608 bf16
  // kmat/vmat overlay the (dead-after-stage1) weffT_hi region:
  float* kmat = ws + 3016704;             // 2097152 f32
  float* vmat = ws + 5113856;             // 2097152 f32
  unsigned short* mgh = (unsigned short*)(ws + 11405312); // 2097152 bf16
  unsigned short* mgl = (unsigned short*)(ws + 12453888);

  // stage 1: mean over Lp (linearity) -> split bf16
  k_part<<<2048, 256, 0, stream>>>(memory, part);
  k_mean_split<<<512, 256, 0, stream>>>(part, mmh, mml);

  // operand prep
  k_splitA<<<128, 256, 0, stream>>>(query, qh, ql);
  k_splitWT<<<dim3(8, 8, 6), 256, 0, stream>>>(Wq_c, Wk_c, Wq, Wk, Wv, Wp,
                                               WTh, WTl);

  // channel-attention projections (MFMA)
  mgemm<<<dim3(8, 8), 256, 0, stream>>>(qh, ql, WTh, WTl, nullptr, qlin, 512, 512);
  mgemm<<<dim3(4, 8), 256, 0, stream>>>(mmh, mml, WTh + 262144, WTl + 262144,
                                        nullptr, kclin, 512, 512);

  // channel softmax -> w_sum -> transposed split W_eff
  k_ch<<<64, 256, 0, stream>>>(qlin, kclin, wsum);
  k_weff<<<256, 256, 0, stream>>>(wsum, Wv_c, wth, wtl);

  // stage-1 aggregation GEMM (MFMA, K=2048) -> split magg
  k_stage1m<<<512, 256, 0, stream>>>(memory, wth, wtl, mgh, mgl);

  // stage-2 projections (MFMA). NOTE: q2 written before kmat overlays weffT.
  mgemm<<<dim3(8, 8), 256, 0, stream>>>(qh, ql, WTh + 2 * 262144,
                                        WTl + 2 * 262144, nullptr, q2, 512, 512);
  mgemm<<<dim3(64, 8), 256, 0, stream>>>(mgh, mgl, WTh + 3 * 262144,
                                         WTl + 3 * 262144, nullptr, kmat, 512, 512);
  mgemm<<<dim3(64, 8), 256, 0, stream>>>(mgh, mgl, WTh + 4 * 262144,
                                         WTl + 4 * 262144, nullptr, vmat, 512, 512);

  // attention (f32) -> split attn, then output projection + bias (MFMA)
  k_attn<<<64, 256, 0, stream>>>(q2, kmat, vmat, ath, atl);
  mgemm<<<dim3(8, 8), 256, 0, stream>>>(ath, atl, WTh + 5 * 262144,
                                        WTl + 5 * 262144, bp, out, 512, 512);
}